// Round 1
// baseline (312.360 us; speedup 1.0000x reference)
//
#include <hip/hip_runtime.h>
#include <hip/hip_bf16.h>

#define HH   4096      // canvas side
#define KK   32        // box / tile side
#define OH   4065      // HH - KK + 1
#define RCHUNK 128     // output rows per pass-1 block

// ---------------- Pass 1: fused dist + vertical 32-row sliding box-sum ----------------
// vsum[r][j] = sum_{t=0..31} dist[r+t][j],  r in [0,OH), j in [0,HH)
__global__ __launch_bounds__(256) void pass1_vert(
    const float* __restrict__ img,   // 32x32
    const float* __restrict__ som,   // 4096x4096
    const float* __restrict__ var,   // 4096x4096
    float* __restrict__ vsum)        // OH x 4096 (pitch 4096)
{
    __shared__ float simg[KK * KK];  // 4 KB
    for (int i = threadIdx.x; i < KK * KK; i += 256) simg[i] = img[i];
    __syncthreads();

    const int j  = blockIdx.x * 256 + threadIdx.x;   // column, always < 4096
    const int jc = j & (KK - 1);
    const int r0 = blockIdx.y * RCHUNK;              // multiple of 32
    const int r_end = min(r0 + RCHUNK, OH);

    float ring[KK];
    float sum = 0.f;

    // init window: rows r0 .. r0+31
#pragma unroll
    for (int t = 0; t < KK; ++t) {
        const int row = r0 + t;
        const float s  = som[row * HH + j];
        const float v  = var[row * HH + j];
        const float im = simg[((row & (KK - 1)) << 5) | jc];
        const float e  = im - s;
        const float d  = (e * e) / (v + 1e-8f);
        ring[t] = d;
        sum += d;
    }

    for (int g = 0; g < RCHUNK / KK; ++g) {
#pragma unroll
        for (int t = 0; t < KK; ++t) {
            const int r = r0 + g * KK + t;
            if (r < r_end) {
                vsum[r * HH + j] = sum;
                if (r + 1 < r_end) {
                    const int row = r + KK;          // <= 4095 guaranteed
                    const float s  = som[row * HH + j];
                    const float v  = var[row * HH + j];
                    const float im = simg[((row & (KK - 1)) << 5) | jc];
                    const float e  = im - s;
                    const float d  = (e * e) / (v + 1e-8f);
                    sum += d - ring[t];              // ring[t] == dist(r)
                    ring[t] = d;                     // becomes dist(r+32)
                }
            }
        }
    }
}

// ---------------- Pass 2: horizontal 32-col sliding box-sum ----------------
// out[r][c] = sum_{t=0..31} vsum[r][c+t],  r,c in [0,OH)
#define P2_RT 64              // rows per tile
#define P2_CT 128             // output cols per tile
#define P2_IC (P2_CT + KK - 1)  // 159 input cols
#define P2_IP 161             // input LDS pitch  (row*161+c -> bank (row+c)%32, conflict-free)
#define P2_OP 129             // output LDS pitch (row*129+c -> bank (row+c)%32, conflict-free)

__global__ __launch_bounds__(256) void pass2_horiz(
    const float* __restrict__ vsum,  // OH x 4096
    float* __restrict__ out)         // OH x OH
{
    __shared__ float sin_[P2_RT * P2_IP];  // 41.2 KB
    __shared__ float sout[P2_RT * P2_OP];  // 33.0 KB

    const int c0 = blockIdx.x * P2_CT;
    const int r0 = blockIdx.y * P2_RT;
    const int tid  = threadIdx.x;
    const int lane = tid & 63;

    // --- stage input tile (coalesced 64-wide rows) ---
    for (int rr = tid >> 6; rr < P2_RT; rr += 4) {
        const int gr = r0 + rr;
        for (int cc = lane; cc < P2_IC; cc += 64) {
            const int gc = c0 + cc;
            float v = 0.f;
            if (gr < OH && gc < HH) v = vsum[gr * HH + gc];
            sin_[rr * P2_IP + cc] = v;
        }
    }
    __syncthreads();

    // --- per-thread horizontal sliding window in LDS ---
    {
        const int row  = tid & 63;       // 0..63
        const int seg  = tid >> 6;       // 0..3
        const int base = seg * 32;
        const float* inrow = &sin_[row * P2_IP];
        float* outrow = &sout[row * P2_OP];

        float w = 0.f;
#pragma unroll
        for (int t = 0; t < KK; ++t) w += inrow[base + t];
        outrow[base] = w;
#pragma unroll
        for (int k = 1; k < 32; ++k) {
            w += inrow[base + KK - 1 + k] - inrow[base + k - 1];
            outrow[base + k] = w;
        }
    }
    __syncthreads();

    // --- coalesced store of output tile ---
    for (int i = tid; i < P2_RT * P2_CT; i += 256) {
        const int rr = i >> 7;          // /128
        const int cc = i & 127;
        const int gr = r0 + rr;
        const int gc = c0 + cc;
        if (gr < OH && gc < OH) out[gr * OH + gc] = sout[rr * P2_OP + cc];
    }
}

extern "C" void kernel_launch(void* const* d_in, const int* in_sizes, int n_in,
                              void* d_out, int out_size, void* d_ws, size_t ws_size,
                              hipStream_t stream) {
    const float* img = (const float*)d_in[0];   // 32x32
    const float* som = (const float*)d_in[1];   // 4096x4096
    const float* var = (const float*)d_in[2];   // 4096x4096
    float* out  = (float*)d_out;                // 4065x4065
    float* vsum = (float*)d_ws;                 // OH x 4096 floats = 66.6 MB

    dim3 blk(256);
    dim3 g1(HH / 256, (OH + RCHUNK - 1) / RCHUNK);        // 16 x 32
    hipLaunchKernelGGL(pass1_vert, g1, blk, 0, stream, img, som, var, vsum);

    dim3 g2((OH + P2_CT - 1) / P2_CT, (OH + P2_RT - 1) / P2_RT);  // 32 x 64
    hipLaunchKernelGGL(pass2_horiz, g2, blk, 0, stream, vsum, out);
}

// Round 2
// 205.954 us; speedup vs baseline: 1.5166x; 1.5166x over previous
//
#include <hip/hip_runtime.h>
#include <hip/hip_bf16.h>

#define HH 4096      // canvas side
#define KK 32        // box / tile side
#define OH 4065      // HH - KK + 1
#define NB 225       // output cols per band (256 input cols - 31)
#define BC 256       // input cols per block == threads
#define RCHUNK 64    // output rows per block
#define GR 8         // output rows per LDS group

// Fused: dist = (tile(img)-som)^2/(var+eps), then 32x32 stride-1 box-sum.
// Vertical window: per-thread register ring (branch-free, fully unrolled).
// Horizontal window: per-group LDS prefix-scan, out = P[c+31]-P[c-1].
__global__ __launch_bounds__(256, 4) void som_fused(
    const float* __restrict__ img,   // 32x32
    const float* __restrict__ som,   // 4096x4096
    const float* __restrict__ var,   // 4096x4096
    float* __restrict__ out)         // 4065x4065
{
    __shared__ float simg[KK * KK];        // 4 KB
    __shared__ float ldsv[2][GR][BC];      // 16 KB, double-buffered column sums
    __shared__ float ldsp[GR][BC];         // 8 KB, prefix sums

    const int tid  = threadIdx.x;
    const int lane = tid & 63;
    const int wv   = tid >> 6;             // wave id 0..3

    for (int i = tid; i < KK * KK; i += BC) simg[i] = img[i];

    const int c0   = blockIdx.x * NB;
    const int col  = c0 + tid;
    const int colc = col < HH ? col : HH - 1;   // clamp (last band only)
    const int jc   = col & (KK - 1);            // thread-constant img col
    const int r0   = blockIdx.y * RCHUNK;

    __syncthreads();

    // ---- init vertical window: rows r0 .. r0+31 (always <= 4063, no clamp) ----
    float ring[KK];
    float sum = 0.f;
#pragma unroll
    for (int t = 0; t < KK; ++t) {
        const int row = r0 + t;
        const float s  = som[row * HH + colc];
        const float v  = var[row * HH + colc];
        const float im = simg[((row & (KK - 1)) << 5) | jc];
        const float e  = im - s;
        const float d  = e * e * __builtin_amdgcn_rcpf(v + 1e-8f);
        ring[t] = d;
        sum += d;
    }

#pragma unroll
    for (int gi = 0; gi < RCHUNK / KK; ++gi) {
#pragma unroll
        for (int sg = 0; sg < KK / GR; ++sg) {
            const int buf = sg & 1;
            // ---- phase A: emit GR column-sums, advance ring (branch-free) ----
#pragma unroll
            for (int k = 0; k < GR; ++k) {
                ldsv[buf][k][tid] = sum;     // vsum for output row r0+gi*32+sg*8+k
                int row = r0 + gi * KK + sg * GR + k + KK;
                row = row < HH ? row : HH - 1;           // clamp, affects only r>=4065 outputs
                const float s  = som[row * HH + colc];
                const float v  = var[row * HH + colc];
                const float im = simg[((row & (KK - 1)) << 5) | jc];
                const float e  = im - s;
                const float d  = e * e * __builtin_amdgcn_rcpf(v + 1e-8f);
                sum += d - ring[sg * GR + k];            // static ring index
                ring[sg * GR + k] = d;
            }
            __syncthreads();

            // ---- phase B: inclusive prefix-scan of each of GR rows (1 wave per 2 rows) ----
#pragma unroll
            for (int rr = 0; rr < 2; ++rr) {
                const int k = 2 * wv + rr;
                float4 x = *(const float4*)&ldsv[buf][k][lane * 4];
                const float p0 = x.x;
                const float p1 = p0 + x.y;
                const float p2 = p1 + x.z;
                const float p3 = p2 + x.w;
                float sc = p3;
#pragma unroll
                for (int off = 1; off < 64; off <<= 1) {
                    const float t = __shfl_up(sc, off, 64);
                    sc += (lane >= off) ? t : 0.f;
                }
                const float excl = sc - p3;              // exclusive prefix of chunk
                float4 o;
                o.x = p0 + excl; o.y = p1 + excl; o.z = p2 + excl; o.w = p3 + excl;
                *(float4*)&ldsp[k][lane * 4] = o;
            }
            __syncthreads();

            // ---- phase C: horizontal window from prefix, coalesced store ----
            if (tid < NB && c0 + tid < OH) {
                const int c = tid;
                const float lo = (c > 0) ? ldsp[0][c - 1] : 0.f;  // dummy touch pattern below
#pragma unroll
                for (int k = 0; k < GR; ++k) {
                    const int rout = r0 + gi * KK + sg * GR + k;
                    if (rout < OH) {
                        const float hi = ldsp[k][c + KK - 1];
                        const float l2 = (c > 0) ? ldsp[k][c - 1] : 0.f;
                        out[rout * OH + c0 + c] = hi - l2;
                    }
                }
                (void)lo;
            }
        }
    }
}

extern "C" void kernel_launch(void* const* d_in, const int* in_sizes, int n_in,
                              void* d_out, int out_size, void* d_ws, size_t ws_size,
                              hipStream_t stream) {
    (void)in_sizes; (void)n_in; (void)out_size; (void)d_ws; (void)ws_size;
    const float* img = (const float*)d_in[0];   // 32x32
    const float* som = (const float*)d_in[1];   // 4096x4096
    const float* var = (const float*)d_in[2];   // 4096x4096
    float* out = (float*)d_out;                 // 4065x4065

    dim3 blk(BC);
    dim3 grd((OH + NB - 1) / NB,                // 19 column bands
             (OH + RCHUNK - 1) / RCHUNK);       // 64 row chunks
    hipLaunchKernelGGL(som_fused, grd, blk, 0, stream, img, som, var, out);
}

// Round 3
// 200.201 us; speedup vs baseline: 1.5602x; 1.0287x over previous
//
#include <hip/hip_runtime.h>
#include <hip/hip_bf16.h>

#define HH 4096      // canvas side
#define KK 32        // box / tile side
#define OH 4065      // HH - KK + 1
#define NB 225       // output cols per band (256 input cols - 31)
#define BC 256       // input cols per block == threads
#define RCHUNK 64    // output rows per block
#define GR 8         // output rows per LDS group
#define NSUB (RCHUNK / GR)   // 8 groups

// Barrier that drains ONLY LDS (lgkmcnt). Global prefetch loads stay in
// flight across it — __syncthreads() would s_waitcnt vmcnt(0) and kill the
// software pipeline. asm memory clobbers stop compiler-level reordering.
__device__ __forceinline__ void barrier_lds_only() {
    asm volatile("" ::: "memory");
    __builtin_amdgcn_s_waitcnt(0xC07F);   // vmcnt(63) expcnt(7) lgkmcnt(0)
    __builtin_amdgcn_s_barrier();
    asm volatile("" ::: "memory");
}

__global__ __launch_bounds__(BC, 4) void som_fused(
    const float* __restrict__ img,   // 32x32
    const float* __restrict__ som,   // 4096x4096
    const float* __restrict__ var,   // 4096x4096
    float* __restrict__ out)         // 4065x4065
{
    __shared__ float simg[KK * KK];        // 4 KB
    __shared__ float ldsv[2][GR][BC];      // 16 KB (scan done in place)

    const int tid  = threadIdx.x;
    const int lane = tid & 63;
    const int wv   = tid >> 6;

    for (int i = tid; i < KK * KK; i += BC) simg[i] = img[i];
    __syncthreads();                       // once; full barrier is fine here

    const int c0   = blockIdx.x * NB;
    const int col  = c0 + tid;
    const int colc = col < HH ? col : HH - 1;   // clamp (last band only)
    const int jc   = col & (KK - 1);
    const int r0   = blockIdx.y * RCHUNK;       // multiple of 32
    const int maxoff = HH - 1 - r0;             // uniform row-offset clamp

    const float* sp = som + (size_t)r0 * HH + colc;
    const float* vp = var + (size_t)r0 * HH + colc;

    // ---- init vertical window: rows r0 .. r0+31 (exposed once per block) ----
    float ring[KK];
    float sum = 0.f;
#pragma unroll
    for (int t = 0; t < KK; ++t) {
        const float s  = sp[t * HH];
        const float v  = vp[t * HH];
        const float im = simg[(t << 5) | jc];   // (r0+t)&31 == t (r0 % 32 == 0)
        const float e  = im - s;
        const float d  = e * e * __builtin_amdgcn_rcpf(v + 1e-8f);
        ring[t] = d;
        sum += d;
    }

    // ---- prefetch group 0 (rows r0+32 .. r0+39) into bank 0 ----
    float pf_s[2][GR], pf_v[2][GR];
#pragma unroll
    for (int k = 0; k < GR; ++k) {
        const int off = KK + k;                 // <= 39 <= maxoff always
        pf_s[0][k] = sp[off * HH];
        pf_v[0][k] = vp[off * HH];
    }

#pragma unroll
    for (int sub = 0; sub < NSUB; ++sub) {
        const int buf = sub & 1;

        // ---- issue prefetch for group sub+1 into the other bank ----
#pragma unroll
        for (int k = 0; k < GR; ++k) {
            int off = KK + (sub + 1) * GR + k;
            off = off <= maxoff ? off : maxoff; // clamped rows only feed rout>=4065
            pf_s[buf ^ 1][k] = sp[off * HH];
            pf_v[buf ^ 1][k] = vp[off * HH];
        }

        // ---- phase A: emit GR column sums, slide window (branch-free) ----
#pragma unroll
        for (int k = 0; k < GR; ++k) {
            ldsv[buf][k][tid] = sum;            // vsum for row r0+sub*GR+k
            const float s  = pf_s[buf][k];
            const float v  = pf_v[buf][k];
            const float im = simg[(((sub * GR + k) & (KK - 1)) << 5) | jc]; // static offset
            const float e  = im - s;
            const float d  = e * e * __builtin_amdgcn_rcpf(v + 1e-8f);
            const int ri   = (sub * GR + k) & (KK - 1);   // static ring index
            sum += d - ring[ri];
            ring[ri] = d;
        }
        barrier_lds_only();

        // ---- phase B: in-place inclusive prefix scan, 2 rows per wave ----
#pragma unroll
        for (int rr = 0; rr < 2; ++rr) {
            const int k = 2 * wv + rr;
            float4 x = *(const float4*)&ldsv[buf][k][lane * 4];
            const float p0 = x.x;
            const float p1 = p0 + x.y;
            const float p2 = p1 + x.z;
            const float p3 = p2 + x.w;
            float sc = p3;
#pragma unroll
            for (int off = 1; off < 64; off <<= 1) {
                const float t = __shfl_up(sc, off, 64);
                sc += (lane >= off) ? t : 0.f;
            }
            const float excl = sc - p3;
            float4 o;
            o.x = p0 + excl; o.y = p1 + excl; o.z = p2 + excl; o.w = p3 + excl;
            *(float4*)&ldsv[buf][k][lane * 4] = o;
        }
        barrier_lds_only();

        // ---- phase C: horizontal window = P[c+31] - P[c-1], coalesced store ----
        if (tid < NB && col < OH) {
#pragma unroll
            for (int k = 0; k < GR; ++k) {
                const int rout = r0 + sub * GR + k;
                if (rout < OH) {
                    const float hi = ldsv[buf][k][tid + KK - 1];
                    const float lo = (tid > 0) ? ldsv[buf][k][tid - 1] : 0.f;
                    out[(size_t)rout * OH + col] = hi - lo;
                }
            }
        }
        // no barrier needed: next group writes the other ldsv bank; the two
        // barriers of group sub+1 order this phase C vs. phase A of sub+2.
    }
}

extern "C" void kernel_launch(void* const* d_in, const int* in_sizes, int n_in,
                              void* d_out, int out_size, void* d_ws, size_t ws_size,
                              hipStream_t stream) {
    (void)in_sizes; (void)n_in; (void)out_size; (void)d_ws; (void)ws_size;
    const float* img = (const float*)d_in[0];   // 32x32
    const float* som = (const float*)d_in[1];   // 4096x4096
    const float* var = (const float*)d_in[2];   // 4096x4096
    float* out = (float*)d_out;                 // 4065x4065

    dim3 blk(BC);
    dim3 grd((OH + NB - 1) / NB,                // 19 column bands
             (OH + RCHUNK - 1) / RCHUNK);       // 64 row chunks
    hipLaunchKernelGGL(som_fused, grd, blk, 0, stream, img, som, var, out);
}